// Round 1
// baseline (524.012 us; speedup 1.0000x reference)
//
#include <hip/hip_runtime.h>

// ---------------------------------------------------------------------------
// Smolgen pipeline, round 3:
//   - K3/K4 rebuilt as 2-phase prefetch GEMM (BK=32, double-buffered LDS,
//     STAGE(t+1) issued before compute(t), one drain barrier per K-step).
//   - All MFMA calls operand-swapped (C computed transposed): lane then holds
//     4 consecutive output COLUMNS -> vectorized stores (f32x4 / 8B bf16x4)
//     instead of scalar dword / 2-byte stores. Bitwise-identical math.
//   - K4/K3 grid linearized + bijective XCD-chunk swizzle (grid%8==0) so each
//     XCD keeps its A row-panel + full B (3 MB) L2-resident.
// MFMA 16x16x32 bf16 mapping: lane l: col16=l&15, quad=l>>4;
//   first operand supplies C's row-dim (quad*4+r), second supplies col16 dim.
// ---------------------------------------------------------------------------

typedef unsigned short ushort_t;
typedef __attribute__((ext_vector_type(8))) short bf16x8;
typedef __attribute__((ext_vector_type(4))) float f32x4;
typedef __attribute__((ext_vector_type(4))) unsigned int u32x4;
typedef __attribute__((ext_vector_type(2))) unsigned int u32x2;

#define MFMA16(a, b, c) __builtin_amdgcn_mfma_f32_16x16x32_bf16((a), (b), (c), 0, 0, 0)

__device__ __forceinline__ unsigned bfround(float f) {
  unsigned u = __builtin_bit_cast(unsigned, f);
  return u + 0x7fffu + ((u >> 16) & 1u);   // RNE to bf16 in the high 16 bits
}
__device__ __forceinline__ unsigned pack2(float lo, float hi) {
  return (bfround(lo) >> 16) | (bfround(hi) & 0xffff0000u);
}

// async global->LDS, 16B per lane; lds dst = wave-uniform base + lane*16
__device__ __forceinline__ void gld16(const ushort_t* g, ushort_t* l) {
  __builtin_amdgcn_global_load_lds(
      (const __attribute__((address_space(1))) unsigned int*)g,
      (__attribute__((address_space(3))) unsigned int*)l, 16, 0, 0);
}

// ------------------------- weight conversion (once) ------------------------
__global__ __launch_bounds__(256) void k_cvt(const float* __restrict__ Wtc,
                                             const float* __restrict__ Wgc,
                                             const float* __restrict__ Wh,
                                             const float* __restrict__ Wl,
                                             ushort_t* __restrict__ oTc,
                                             ushort_t* __restrict__ oGc,
                                             ushort_t* __restrict__ oWh,
                                             ushort_t* __restrict__ oWl) {
  size_t g = (size_t)blockIdx.x * 256 + threadIdx.x;  // group of 8 elements
  const float* src; ushort_t* dst; size_t off;
  if (g < 4096)        { src = Wtc; dst = oTc; off = g; }
  else if (g < 69632)  { src = Wgc; dst = oGc; off = g - 4096; }
  else if (g < 200704) { src = Wh;  dst = oWh; off = g - 69632; }
  else                 { src = Wl;  dst = oWl; off = g - 200704; }
  float4 f0 = ((const float4*)src)[off * 2];
  float4 f1 = ((const float4*)src)[off * 2 + 1];
  u32x4 p;
  p.x = pack2(f0.x, f0.y); p.y = pack2(f0.z, f0.w);
  p.z = pack2(f1.x, f1.y); p.w = pack2(f1.z, f1.w);
  ((u32x4*)dst)[off] = p;
}

// --------------------------- K1: token compress ----------------------------
// One block per batch b; x streamed global->regs (lane loads its own frag),
// Wtc_bf staged in LDS per 256-K chunk. Swapped MFMA: lane holds 4 consecutive
// k outputs for one token -> 8B packed stores.
__global__ __launch_bounds__(256) void k_tok(const float* __restrict__ x,
                                             const ushort_t* __restrict__ WtcBf,
                                             ushort_t* __restrict__ flatBf) {
  __shared__ ushort_t lb[32][264];  // 32 rows x 256 K-chunk (+8 pad)
  const int t = threadIdx.x;
  const int w = t >> 6, l = t & 63, col16 = l & 15, quad = l >> 4;
  const float* arow = x + (size_t)blockIdx.x * 65536 + (size_t)(w * 16 + col16) * 1024;
  f32x4 acc0 = {0.f, 0.f, 0.f, 0.f}, acc1 = {0.f, 0.f, 0.f, 0.f};

  for (int ko = 0; ko < 1024; ko += 256) {
    // A loads for this chunk first (independent of LDS) — latency overlaps staging
    float4 af[16];
#pragma unroll
    for (int s = 0; s < 8; ++s) {
      af[2 * s]     = *(const float4*)(arow + ko + s * 32 + quad * 8);
      af[2 * s + 1] = *(const float4*)(arow + ko + s * 32 + quad * 8 + 4);
    }
    __syncthreads();
    {  // stage W chunk: 32 rows x 256 bf16, 64 B per thread
      int r = t >> 3, c0 = (t & 7) * 32;
      const ushort_t* src = WtcBf + (size_t)r * 1024 + ko + c0;
#pragma unroll
      for (int c = 0; c < 4; ++c)
        *(bf16x8*)&lb[r][c0 + c * 8] = *(const bf16x8*)(src + c * 8);
    }
    __syncthreads();
#pragma unroll
    for (int s = 0; s < 8; ++s) {
      u32x4 p;
      p.x = pack2(af[2 * s].x, af[2 * s].y);
      p.y = pack2(af[2 * s].z, af[2 * s].w);
      p.z = pack2(af[2 * s + 1].x, af[2 * s + 1].y);
      p.w = pack2(af[2 * s + 1].z, af[2 * s + 1].w);
      bf16x8 a = __builtin_bit_cast(bf16x8, p);
      bf16x8 b0 = *(const bf16x8*)&lb[col16][s * 32 + quad * 8];
      bf16x8 b1 = *(const bf16x8*)&lb[16 + col16][s * 32 + quad * 8];
      acc0 = MFMA16(b0, a, acc0);   // swapped: C[k][token]
      acc1 = MFMA16(b1, a, acc1);
    }
  }
  // lane: token m = w*16+col16, k = quad*4+r (acc0), 16+quad*4+r (acc1)
  ushort_t* ob = flatBf + (size_t)blockIdx.x * 2048;
  const int m = w * 16 + col16;
  u32x2 v0, v1;
  v0.x = pack2(acc0[0], acc0[1]); v0.y = pack2(acc0[2], acc0[3]);
  v1.x = pack2(acc1[0], acc1[1]); v1.y = pack2(acc1[2], acc1[3]);
  *(u32x2*)&ob[m * 32 + quad * 4] = v0;
  *(u32x2*)&ob[m * 32 + 16 + quad * 4] = v1;
}

// ------------------ K2a: global compress, split-K partials -----------------
// grid (64 m-blocks, 4 k-slices of 512). BM=16, N=256, BK=32.
// Swapped MFMA: lane holds 4 consecutive n -> f32x4 stores.
__global__ __launch_bounds__(256) void k_gc_part(const ushort_t* __restrict__ Abf,
                                                 const ushort_t* __restrict__ Bbf,
                                                 float* __restrict__ Hpart) {
  __shared__ ushort_t la[16][40];
  __shared__ ushort_t lb[256][40];
  const int t = threadIdx.x;
  const int w = t >> 6, l = t & 63, col16 = l & 15, quad = l >> 4;
  const int b0 = blockIdx.x * 16;
  const int k0 = blockIdx.y * 512;
  f32x4 acc[4];
#pragma unroll
  for (int j = 0; j < 4; ++j) acc[j] = (f32x4){0.f, 0.f, 0.f, 0.f};

  for (int kk = 0; kk < 512; kk += 32) {
    __syncthreads();
    if (t < 128) {  // A: 16 rows x 32 bf16
      int r = t >> 3, c0 = (t & 7) * 4;
      *(ushort4*)&la[r][c0] =
          *(const ushort4*)(Abf + (size_t)(b0 + r) * 2048 + k0 + kk + c0);
    }
    {  // B: 256 rows x 32 bf16, one row per thread
      const ushort_t* src = Bbf + (size_t)t * 2048 + k0 + kk;
#pragma unroll
      for (int c = 0; c < 4; ++c)
        *(bf16x8*)&lb[t][c * 8] = *(const bf16x8*)(src + c * 8);
    }
    __syncthreads();
    bf16x8 af = *(const bf16x8*)&la[col16][quad * 8];
#pragma unroll
    for (int j = 0; j < 4; ++j) {
      bf16x8 bfj = *(const bf16x8*)&lb[w * 64 + j * 16 + col16][quad * 8];
      acc[j] = MFMA16(bfj, af, acc[j]);   // swapped: C[n][m]
    }
  }
  // lane: batch row b0+col16, cols w*64 + j*16 + quad*4 .. +3
  float* o = Hpart + (size_t)blockIdx.y * 262144;  // 1024*256 per slice
#pragma unroll
  for (int j = 0; j < 4; ++j)
    *(f32x4*)&o[(size_t)(b0 + col16) * 256 + w * 64 + j * 16 + quad * 4] = acc[j];
}

// ---------------- K2b: reduce partials + bias + RMSNorm -> bf16 ------------
__global__ __launch_bounds__(256) void k_gc_red(const float* __restrict__ Hpart,
                                                const float* __restrict__ bias,
                                                const float* __restrict__ rscale,
                                                ushort_t* __restrict__ gBf) {
  __shared__ float lred[16][17];
  __shared__ float linv[16];
  const int t = threadIdx.x;
  const int row = t >> 4, seg = t & 15;
  const size_t base = (size_t)(blockIdx.x * 16 + row) * 256 + seg * 16;
  float v[16];
#pragma unroll
  for (int k = 0; k < 4; ++k) {
    float4 s0 = *(const float4*)(Hpart + base + k * 4);
    float4 s1 = *(const float4*)(Hpart + 262144 + base + k * 4);
    float4 s2 = *(const float4*)(Hpart + 524288 + base + k * 4);
    float4 s3 = *(const float4*)(Hpart + 786432 + base + k * 4);
    float4 bi = *(const float4*)(bias + seg * 16 + k * 4);
    v[k * 4 + 0] = s0.x + s1.x + s2.x + s3.x + bi.x;
    v[k * 4 + 1] = s0.y + s1.y + s2.y + s3.y + bi.y;
    v[k * 4 + 2] = s0.z + s1.z + s2.z + s3.z + bi.z;
    v[k * 4 + 3] = s0.w + s1.w + s2.w + s3.w + bi.w;
  }
  float ss = 0.f;
#pragma unroll
  for (int k = 0; k < 16; ++k) ss += v[k] * v[k];
  lred[row][seg] = ss;
  __syncthreads();
  if (t < 16) {
    float s = 0.f;
#pragma unroll
    for (int k = 0; k < 16; ++k) s += lred[t][k];
    linv[t] = 1.0f / sqrtf(s * (1.0f / 256.0f) + 1e-6f);
  }
  __syncthreads();
  float iv = linv[row];
  float rs[16];
#pragma unroll
  for (int k = 0; k < 4; ++k)
    *(float4*)&rs[k * 4] = *(const float4*)(rscale + seg * 16 + k * 4);
  u32x4 p0, p1;
  p0.x = pack2(v[0] * iv * rs[0],  v[1] * iv * rs[1]);
  p0.y = pack2(v[2] * iv * rs[2],  v[3] * iv * rs[3]);
  p0.z = pack2(v[4] * iv * rs[4],  v[5] * iv * rs[5]);
  p0.w = pack2(v[6] * iv * rs[6],  v[7] * iv * rs[7]);
  p1.x = pack2(v[8] * iv * rs[8],  v[9] * iv * rs[9]);
  p1.y = pack2(v[10] * iv * rs[10], v[11] * iv * rs[11]);
  p1.z = pack2(v[12] * iv * rs[12], v[13] * iv * rs[13]);
  p1.w = pack2(v[14] * iv * rs[14], v[15] * iv * rs[15]);
  *(u32x4*)(gBf + base) = p0;
  *(u32x4*)(gBf + base + 8) = p1;
}

// -------- K3/K4: (Mx256)bf16 @ (4096x256)bf16^T, 2-phase prefetch ----------
// 128x128 tile, 2x2 waves of 64x64, BK=32, double-buffered LDS (4x8KB=32KB).
// Per K-step: issue STAGE(t+1) -> ds_read+MFMA(t) -> barrier (drains vmcnt:
// stage latency hides under compute). XOR chunk swizzle (chunk=16B=8bf16):
// LDS pos r*4+p holds global chunk p^(r&3) of row r -> even bank load.
// Swapped MFMA -> lane holds 4 consecutive output cols: f32x4 / 8B stores.
// 1-D grid with bijective XCD chunk swizzle (grid % 8 == 0).
template <bool OBF>
__global__ __launch_bounds__(256) void k_gemm(const ushort_t* __restrict__ A,
                                              const ushort_t* __restrict__ Bw,
                                              float* __restrict__ Cf,
                                              ushort_t* __restrict__ Cb) {
  __shared__ ushort_t la[2][4096];   // 128 rows x 32 bf16 per buffer
  __shared__ ushort_t lb[2][4096];
  const int t = threadIdx.x;
  const int w = t >> 6, l = t & 63, col16 = l & 15, quad = l >> 4;
  const int wm = w >> 1, wn = w & 1;
  const int id = blockIdx.x;
  const int id2 = (id & 7) * ((int)gridDim.x >> 3) + (id >> 3);  // XCD chunks
  const size_t am0 = (size_t)(id2 >> 5) * 128;   // row-tile
  const size_t bn0 = (size_t)(id2 & 31) * 128;   // col-tile

  f32x4 acc[4][4];
#pragma unroll
  for (int i = 0; i < 4; ++i)
#pragma unroll
    for (int j = 0; j < 4; ++j) acc[i][j] = (f32x4){0.f, 0.f, 0.f, 0.f};

  auto STAGE = [&](int buf, int kk) {
#pragma unroll
    for (int i = 0; i < 2; ++i) {
      int L = i * 256 + t;                 // chunk index 0..511
      int r = L >> 2;                      // row 0..127
      int cs = (L & 3) ^ (r & 3);          // swizzled global chunk
      ushort_t* da = &la[buf][(size_t)(i * 256 + (w << 6)) * 8];  // wave base
      ushort_t* db = &lb[buf][(size_t)(i * 256 + (w << 6)) * 8];
      gld16(A + (am0 + r) * 256 + kk + cs * 8, da);
      gld16(Bw + (bn0 + r) * 256 + kk + cs * 8, db);
    }
  };

  STAGE(0, 0);
  __syncthreads();                         // drain prologue stage
#pragma unroll
  for (int tix = 0; tix < 8; ++tix) {
    const int buf = tix & 1;
    if (tix < 7) STAGE(buf ^ 1, (tix + 1) * 32);   // prefetch next K-step
    bf16x8 af[4], bfv[4];
#pragma unroll
    for (int i = 0; i < 4; ++i) {
      int R = wm * 64 + i * 16 + col16;
      af[i] = *(const bf16x8*)&la[buf][(size_t)((R << 2) + (quad ^ (R & 3))) * 8];
    }
#pragma unroll
    for (int j = 0; j < 4; ++j) {
      int R = wn * 64 + j * 16 + col16;
      bfv[j] = *(const bf16x8*)&lb[buf][(size_t)((R << 2) + (quad ^ (R & 3))) * 8];
    }
#pragma unroll
    for (int i = 0; i < 4; ++i)
#pragma unroll
      for (int j = 0; j < 4; ++j)
        acc[i][j] = MFMA16(bfv[j], af[i], acc[i][j]);   // swapped: C^T frag
    __syncthreads();   // drains lgkm (reads of buf) + vmcnt (stage of buf^1)
  }

  // lane: row = am0 + wm*64 + i*16 + col16; cols = bn0 + wn*64 + j*16 + quad*4..+3
#pragma unroll
  for (int i = 0; i < 4; ++i)
#pragma unroll
    for (int j = 0; j < 4; ++j) {
      size_t row = am0 + wm * 64 + i * 16 + col16;
      size_t cc = bn0 + wn * 64 + j * 16 + quad * 4;
      if (OBF) {
        u32x2 v;
        v.x = pack2(acc[i][j][0], acc[i][j][1]);
        v.y = pack2(acc[i][j][2], acc[i][j][3]);
        *(u32x2*)&Cb[row * 4096 + cc] = v;
      } else {
        *(f32x4*)&Cf[row * 4096 + cc] = acc[i][j];
      }
    }
}

// ---------------------------------------------------------------------------
extern "C" void kernel_launch(void* const* d_in, const int* in_sizes, int n_in,
                              void* d_out, int out_size, void* d_ws, size_t ws_size,
                              hipStream_t stream) {
  const float* x   = (const float*)d_in[0];  // (1024,64,1024)
  const float* Wtc = (const float*)d_in[1];  // (32,1024)
  const float* Wgc = (const float*)d_in[2];  // (256,2048)
  const float* bgc = (const float*)d_in[3];  // (256,)
  const float* rsc = (const float*)d_in[4];  // (256,)
  const float* Wh  = (const float*)d_in[5];  // (16,256,256)=(4096,256)
  const float* Wl  = (const float*)d_in[6];  // (4096,256)
  float* out = (float*)d_out;                // (16384,4096) fp32

  char* ws = (char*)d_ws;                    // all offsets 256B-aligned
  ushort_t* oTc    = (ushort_t*)(ws);                    //   64 KB
  ushort_t* oGc    = (ushort_t*)(ws + 65536);            //    1 MB
  ushort_t* oWh    = (ushort_t*)(ws + 1114112);          //    2 MB
  ushort_t* oWl    = (ushort_t*)(ws + 3211264);          //    2 MB
  ushort_t* flatBf = (ushort_t*)(ws + 5308416);          //    4 MB
  ushort_t* gBf    = (ushort_t*)(ws + 9502720);          //  512 KB
  ushort_t* HBf    = (ushort_t*)(ws + 10027008);         //    8 MB
  float*    Hpart  = (float*)(ws + 18415616);            //    4 MB

  k_cvt<<<1296, 256, 0, stream>>>(Wtc, Wgc, Wh, Wl, oTc, oGc, oWh, oWl);
  k_tok<<<1024, 256, 0, stream>>>(x, oTc, flatBf);
  k_gc_part<<<dim3(64, 4), 256, 0, stream>>>(flatBf, oGc, Hpart);
  k_gc_red<<<64, 256, 0, stream>>>(Hpart, bgc, rsc, gBf);
  k_gemm<true><<<256, 256, 0, stream>>>(gBf, oWh, nullptr, HBf);
  k_gemm<false><<<4096, 256, 0, stream>>>(HBf, oWl, out, nullptr);
}